// Round 1
// baseline (1685.024 us; speedup 1.0000x reference)
//
#include <hip/hip_runtime.h>

// Hetero GraphSAGE (3 layers, users<->movies) + JK-cat projection + BN-MLP edge scorer.
// Strategy:
//  - Build CSR (count -> scan -> bin-scatter) once per call; mean-aggregate with
//    one wave per dst node (lane = feature), no float atomics.
//  - All dense per-node GEMMs use a 192-row LDS tile, thread-per-row, k-outer /
//    h-unrolled (acc[] statically indexed -> stays in VGPRs), weight rows are
//    wave-uniform -> scalar loads.
//  - BN stats fused into classifier tiles (block partial sums -> global atomics),
//    finalized to scale/shift form.

namespace {

constexpr int NUc = 100000;
constexpr int NMc = 20000;
constexpr int HD  = 64;
constexpr int NE  = 1000000;
constexpr int ELc = 500000;
constexpr int NL  = 3;
constexpr float BN_EPS = 1e-5f;

constexpr int TILE = 192;       // rows per block in tile kernels (3 waves)
constexpr int XLS  = 68;        // LDS row stride (floats): 68*4=272 bytes, 16B-aligned, breaks bank conflicts

__global__ void count_kernel(const int* __restrict__ eu, const int* __restrict__ em,
                             int* __restrict__ cu, int* __restrict__ cm) {
  int t = blockIdx.x * 256 + threadIdx.x;
  if (t < NE) {
    atomicAdd(&cu[eu[t]], 1);
    atomicAdd(&cm[em[t]], 1);
  }
}

// single-block exclusive scan: per-thread serial segment + Hillis-Steele over 1024 totals
__global__ void scan_kernel(const int* __restrict__ cnt, int n, int* __restrict__ offs) {
  __shared__ int sums[1024];
  int t = threadIdx.x;
  int seg = (n + 1023) >> 10;
  int lo = t * seg;
  int hi = min(lo + seg, n);
  int s = 0;
  for (int i = lo; i < hi; i++) s += cnt[i];
  sums[t] = s;
  __syncthreads();
  for (int d = 1; d < 1024; d <<= 1) {
    int v  = sums[t];
    int vp = (t >= d) ? sums[t - d] : 0;
    __syncthreads();
    sums[t] = v + vp;
    __syncthreads();
  }
  int run = (t > 0) ? sums[t - 1] : 0;
  for (int i = lo; i < hi; i++) { offs[i] = run; run += cnt[i]; }
  if (t == 1023) offs[n] = sums[1023];
}

__global__ void binscatter_kernel(const int* __restrict__ eu, const int* __restrict__ em,
                                  int* __restrict__ cu, int* __restrict__ cm,
                                  int* __restrict__ su, int* __restrict__ sm) {
  int t = blockIdx.x * 256 + threadIdx.x;
  if (t < NE) {
    int u = eu[t], m = em[t];
    int pm = atomicAdd(&cm[m], 1); sm[pm] = u;  // movie buckets hold user srcs
    int pu = atomicAdd(&cu[u], 1); su[pu] = m;  // user buckets hold movie srcs
  }
}

__global__ void gather_xu0_kernel(const int* __restrict__ n_id, const float* __restrict__ emb,
                                  float* __restrict__ xu0) {
  int t = blockIdx.x * 256 + threadIdx.x;
  if (t < NUc * 16) {
    int n = t >> 4, c = t & 15;
    float4 v = *(const float4*)(emb + (size_t)n_id[n] * HD + c * 4);
    *(float4*)(xu0 + (size_t)n * HD + c * 4) = v;
  }
}

// mean aggregation: one wave per dst node, lane = feature channel
__global__ void aggregate_kernel(const int* __restrict__ offs, const int* __restrict__ ssrc,
                                 const float* __restrict__ xsrc, int xstride,
                                 float* __restrict__ agg, int ndst) {
  int gid  = blockIdx.x * 256 + threadIdx.x;
  int w    = gid >> 6;
  int lane = gid & 63;
  if (w >= ndst) return;
  int s0 = offs[w], s1 = offs[w + 1];
  float acc = 0.f;
  int i = s0;
  for (; i + 4 <= s1; i += 4) {
    int a0 = ssrc[i], a1 = ssrc[i + 1], a2 = ssrc[i + 2], a3 = ssrc[i + 3];
    float v0 = xsrc[(size_t)a0 * xstride + lane];
    float v1 = xsrc[(size_t)a1 * xstride + lane];
    float v2 = xsrc[(size_t)a2 * xstride + lane];
    float v3 = xsrc[(size_t)a3 * xstride + lane];
    acc += v0 + v1 + v2 + v3;
  }
  for (; i < s1; i++) acc += xsrc[(size_t)ssrc[i] * xstride + lane];
  float inv = 1.f / fmaxf((float)(s1 - s0), 1.f);
  agg[(size_t)w * HD + lane] = acc * inv;
}

// out = relu(agg@Wl + x@Wr + b); thread-per-row, 192-row LDS tile
__global__ __launch_bounds__(TILE) void sage_combine_kernel(
    int N, const float* __restrict__ agg,
    const float* __restrict__ xin, int xstride,
    const float* __restrict__ Wl, const float* __restrict__ Wr,
    const float* __restrict__ bias,
    float* __restrict__ out, int ostride) {
  __shared__ float xl[TILE * XLS];
  int t = threadIdx.x;
  int base = blockIdx.x * TILE;
  float acc[64];
#pragma unroll
  for (int h = 0; h < 64; h++) acc[h] = 0.f;

  // ---- chunk A: agg (row stride 64), weights Wl
#pragma unroll
  for (int rep = 0; rep < 16; rep++) {
    int row = rep * 12 + (t >> 4), j = t & 15;
    if (base + row < N)
      *(float4*)&xl[row * XLS + j * 4] = *(const float4*)(agg + (size_t)(base + row) * HD + j * 4);
  }
  __syncthreads();
  for (int k = 0; k < 64; k++) {
    float xv = xl[t * XLS + k];
    const float* w = Wl + k * 64;   // wave-uniform row -> scalar loads
#pragma unroll
    for (int h = 0; h < 64; h++) acc[h] += xv * w[h];
  }
  __syncthreads();
  // ---- chunk B: x_dst, weights Wr
#pragma unroll
  for (int rep = 0; rep < 16; rep++) {
    int row = rep * 12 + (t >> 4), j = t & 15;
    if (base + row < N)
      *(float4*)&xl[row * XLS + j * 4] = *(const float4*)(xin + (size_t)(base + row) * xstride + j * 4);
  }
  __syncthreads();
  for (int k = 0; k < 64; k++) {
    float xv = xl[t * XLS + k];
    const float* w = Wr + k * 64;
#pragma unroll
    for (int h = 0; h < 64; h++) acc[h] += xv * w[h];
  }
  __syncthreads();
#pragma unroll
  for (int h = 0; h < 64; h++) xl[t * XLS + h] = fmaxf(acc[h] + bias[h], 0.f);
  __syncthreads();
#pragma unroll
  for (int rep = 0; rep < 16; rep++) {
    int row = rep * 12 + (t >> 4), j = t & 15;
    if (base + row < N)
      *(float4*)(out + (size_t)(base + row) * ostride + j * 4) = *(const float4*)&xl[row * XLS + j * 4];
  }
}

// h = cat(outs,3)@W + b   (K=192, 3 chunks of 64)
__global__ __launch_bounds__(TILE) void proj_kernel(
    int N, const float* __restrict__ xin, const float* __restrict__ W,
    const float* __restrict__ bias, float* __restrict__ out) {
  __shared__ float xl[TILE * XLS];
  int t = threadIdx.x;
  int base = blockIdx.x * TILE;
  float acc[64];
#pragma unroll
  for (int h = 0; h < 64; h++) acc[h] = 0.f;
  for (int c = 0; c < 3; c++) {
#pragma unroll
    for (int rep = 0; rep < 16; rep++) {
      int row = rep * 12 + (t >> 4), j = t & 15;
      if (base + row < N)
        *(float4*)&xl[row * XLS + j * 4] =
            *(const float4*)(xin + (size_t)(base + row) * (NL * HD) + c * HD + j * 4);
    }
    __syncthreads();
    for (int k = 0; k < 64; k++) {
      float xv = xl[t * XLS + k];
      const float* w = W + (c * 64 + k) * 64;
#pragma unroll
      for (int h = 0; h < 64; h++) acc[h] += xv * w[h];
    }
    __syncthreads();
  }
#pragma unroll
  for (int h = 0; h < 64; h++) xl[t * XLS + h] = acc[h] + bias[h];
  __syncthreads();
#pragma unroll
  for (int rep = 0; rep < 16; rep++) {
    int row = rep * 12 + (t >> 4), j = t & 15;
    if (base + row < N)
      *(float4*)(out + (size_t)(base + row) * HD + j * 4) = *(const float4*)&xl[row * XLS + j * 4];
  }
}

// y1 = cat(h_u[lu], h_m[lm]) @ W1 + b1 ; store y1, accumulate BN column sums
__global__ __launch_bounds__(TILE) void cls1_kernel(
    const float* __restrict__ hu, const float* __restrict__ hm,
    const int* __restrict__ lu, const int* __restrict__ lm,
    const float* __restrict__ W1, const float* __restrict__ b1,
    float* __restrict__ y1, float* __restrict__ sum1, float* __restrict__ ssq1) {
  __shared__ float xl[TILE * XLS];
  int t = threadIdx.x;
  int base = blockIdx.x * TILE;
  float acc[64];
#pragma unroll
  for (int h = 0; h < 64; h++) acc[h] = 0.f;
  for (int c = 0; c < 2; c++) {
    const float* src = c ? hm : hu;
    const int* idx   = c ? lm : lu;
#pragma unroll
    for (int rep = 0; rep < 16; rep++) {
      int row = rep * 12 + (t >> 4), j = t & 15;
      if (base + row < ELc) {
        int g = idx[base + row];
        *(float4*)&xl[row * XLS + j * 4] = *(const float4*)(src + (size_t)g * HD + j * 4);
      }
    }
    __syncthreads();
    for (int k = 0; k < 64; k++) {
      float xv = xl[t * XLS + k];
      const float* w = W1 + (c * 64 + k) * 64;
#pragma unroll
      for (int h = 0; h < 64; h++) acc[h] += xv * w[h];
    }
    __syncthreads();
  }
  bool valid = (base + t) < ELc;
#pragma unroll
  for (int h = 0; h < 64; h++) xl[t * XLS + h] = valid ? (acc[h] + b1[h]) : 0.f;
  __syncthreads();
#pragma unroll
  for (int rep = 0; rep < 16; rep++) {
    int row = rep * 12 + (t >> 4), j = t & 15;
    if (base + row < ELc)
      *(float4*)(y1 + (size_t)(base + row) * HD + j * 4) = *(const float4*)&xl[row * XLS + j * 4];
  }
  if (t < 64) {
    float s = 0.f, ss = 0.f;
    for (int r = 0; r < TILE; r++) {
      float v = xl[r * XLS + t];
      s += v; ss += v * v;
    }
    atomicAdd(&sum1[t], s);
    atomicAdd(&ssq1[t], ss);
  }
}

__global__ void bn_finalize_kernel(const float* __restrict__ sum, const float* __restrict__ ssq,
                                   const float* __restrict__ g, const float* __restrict__ be,
                                   int ncols, float inv_n,
                                   float* __restrict__ scale, float* __restrict__ shift) {
  int t = threadIdx.x;
  if (t < ncols) {
    float m = sum[t] * inv_n;
    float v = ssq[t] * inv_n - m * m;   // biased variance, as torch BN training-mode
    float rstd = rsqrtf(v + BN_EPS);
    float sc = g[t] * rstd;
    scale[t] = sc;
    shift[t] = be[t] - m * sc;
  }
}

// z1 = relu(BN1(y1)); y2 = z1@W2 + b2 ; store y2, accumulate BN2 column sums
__global__ __launch_bounds__(TILE) void cls2_kernel(
    const float* __restrict__ y1, const float* __restrict__ scale1, const float* __restrict__ shift1,
    const float* __restrict__ W2, const float* __restrict__ b2,
    float* __restrict__ y2, float* __restrict__ sum2, float* __restrict__ ssq2) {
  __shared__ float xl[TILE * XLS];
  int t = threadIdx.x;
  int base = blockIdx.x * TILE;
#pragma unroll
  for (int rep = 0; rep < 16; rep++) {
    int row = rep * 12 + (t >> 4), j = t & 15;
    if (base + row < ELc) {
      float4 v  = *(const float4*)(y1 + (size_t)(base + row) * HD + j * 4);
      float4 sc = *(const float4*)(scale1 + j * 4);
      float4 sh = *(const float4*)(shift1 + j * 4);
      v.x = fmaxf(v.x * sc.x + sh.x, 0.f);
      v.y = fmaxf(v.y * sc.y + sh.y, 0.f);
      v.z = fmaxf(v.z * sc.z + sh.z, 0.f);
      v.w = fmaxf(v.w * sc.w + sh.w, 0.f);
      *(float4*)&xl[row * XLS + j * 4] = v;
    }
  }
  __syncthreads();
  float acc[32];
#pragma unroll
  for (int h = 0; h < 32; h++) acc[h] = 0.f;
  for (int k = 0; k < 64; k++) {
    float xv = xl[t * XLS + k];
    const float* w = W2 + k * 32;
#pragma unroll
    for (int h = 0; h < 32; h++) acc[h] += xv * w[h];
  }
  __syncthreads();
  bool valid = (base + t) < ELc;
#pragma unroll
  for (int h = 0; h < 32; h++) xl[t * XLS + h] = valid ? (acc[h] + b2[h]) : 0.f;
  __syncthreads();
#pragma unroll
  for (int rep = 0; rep < 8; rep++) {
    int row = rep * 24 + (t >> 3), j = t & 7;
    if (base + row < ELc)
      *(float4*)(y2 + (size_t)(base + row) * 32 + j * 4) = *(const float4*)&xl[row * XLS + j * 4];
  }
  if (t < 32) {
    float s = 0.f, ss = 0.f;
    for (int r = 0; r < TILE; r++) {
      float v = xl[r * XLS + t];
      s += v; ss += v * v;
    }
    atomicAdd(&sum2[t], s);
    atomicAdd(&ssq2[t], ss);
  }
}

// out = relu(BN2(y2)) @ W3 + b3
__global__ void cls3_kernel(const float* __restrict__ y2, const float* __restrict__ scale2,
                            const float* __restrict__ shift2, const float* __restrict__ W3,
                            const float* __restrict__ b3, float* __restrict__ outp) {
  int r = blockIdx.x * 256 + threadIdx.x;
  if (r >= ELc) return;
  float s = b3[0];
#pragma unroll
  for (int j = 0; j < 32; j++) {
    float v = y2[(size_t)r * 32 + j];
    v = fmaxf(v * scale2[j] + shift2[j], 0.f);
    s += v * W3[j];
  }
  outp[r] = s;
}

}  // namespace

extern "C" void kernel_launch(void* const* d_in, const int* in_sizes, int n_in,
                              void* d_out, int out_size, void* d_ws, size_t ws_size,
                              hipStream_t stream) {
  const int*   n_id    = (const int*)d_in[0];
  const float* movie_x = (const float*)d_in[1];
  const int*   eu      = (const int*)d_in[2];
  const int*   em      = (const int*)d_in[3];
  const int*   lu      = (const int*)d_in[4];
  const int*   lm      = (const int*)d_in[5];
  const float* uemb    = (const float*)d_in[6];
  const float* Wl_um   = (const float*)d_in[7];
  const float* b_um    = (const float*)d_in[8];
  const float* Wr_um   = (const float*)d_in[9];
  const float* Wl_mu   = (const float*)d_in[10];
  const float* b_mu    = (const float*)d_in[11];
  const float* Wr_mu   = (const float*)d_in[12];
  const float* puW     = (const float*)d_in[13];
  const float* pub     = (const float*)d_in[14];
  const float* pmW     = (const float*)d_in[15];
  const float* pmb     = (const float*)d_in[16];
  const float* W1      = (const float*)d_in[17];
  const float* b1      = (const float*)d_in[18];
  const float* g1      = (const float*)d_in[19];
  const float* be1     = (const float*)d_in[20];
  const float* W2      = (const float*)d_in[21];
  const float* b2      = (const float*)d_in[22];
  const float* g2      = (const float*)d_in[23];
  const float* be2     = (const float*)d_in[24];
  const float* W3      = (const float*)d_in[25];
  const float* b3      = (const float*)d_in[26];
  float* outp = (float*)d_out;

  float* ws = (float*)d_ws;
  size_t o = 0;
  float* xu0    = ws + o; o += (size_t)NUc * HD;        // 6.40M f
  float* outs_u = ws + o; o += (size_t)NUc * NL * HD;   // 19.20M f
  float* outs_m = ws + o; o += (size_t)NMc * NL * HD;   //  3.84M f
  float* agg_u  = ws + o; o += (size_t)NUc * HD;        //  6.40M f
  float* agg_m  = ws + o; o += (size_t)NMc * HD;        //  1.28M f  (conv region = 37.12M f)
  float* y1 = ws;  // [EL][64] = 32M f, overlaps conv region (dead before cls1)
  float* y2     = ws + o; o += (size_t)ELc * 32;        // 16.00M f
  float* h_u    = ws + o; o += (size_t)NUc * HD;
  float* h_m    = ws + o; o += (size_t)NMc * HD;
  int* ssrc_u = (int*)(ws + o); o += NE;
  int* ssrc_m = (int*)(ws + o); o += NE;
  int* cnt_u  = (int*)(ws + o); o += NUc;
  int* cnt_m  = (int*)(ws + o); o += NMc;
  int* offs_u = (int*)(ws + o); o += NUc + 64;
  int* offs_m = (int*)(ws + o); o += NMc + 64;
  int* cur_u  = (int*)(ws + o); o += NUc;
  int* cur_m  = (int*)(ws + o); o += NMc;
  float* stats = ws + o; o += 512;
  if (ws_size < o * sizeof(float)) return;  // ws too small -> leave output zeros (diagnostic)

  float* sum1 = stats,        *ssq1 = stats + 64;
  float* sum2 = stats + 128,  *ssq2 = stats + 160;
  float* scale1 = stats + 192, *shift1 = stats + 256;
  float* scale2 = stats + 320, *shift2 = stats + 352;

  hipMemsetAsync(cnt_u, 0, NUc * sizeof(int), stream);
  hipMemsetAsync(cnt_m, 0, NMc * sizeof(int), stream);
  hipMemsetAsync(stats, 0, 192 * sizeof(float), stream);

  int eb = (NE + 255) / 256;
  count_kernel<<<eb, 256, 0, stream>>>(eu, em, cnt_u, cnt_m);
  scan_kernel<<<1, 1024, 0, stream>>>(cnt_u, NUc, offs_u);
  scan_kernel<<<1, 1024, 0, stream>>>(cnt_m, NMc, offs_m);
  hipMemcpyAsync(cur_u, offs_u, NUc * sizeof(int), hipMemcpyDeviceToDevice, stream);
  hipMemcpyAsync(cur_m, offs_m, NMc * sizeof(int), hipMemcpyDeviceToDevice, stream);
  binscatter_kernel<<<eb, 256, 0, stream>>>(eu, em, cur_u, cur_m, ssrc_u, ssrc_m);
  gather_xu0_kernel<<<(NUc * 16 + 255) / 256, 256, 0, stream>>>(n_id, uemb, xu0);

  for (int i = 0; i < NL; i++) {
    const float* xu_prev = (i == 0) ? xu0 : (outs_u + (size_t)(i - 1) * HD);
    const float* xm_prev = (i == 0) ? movie_x : (outs_m + (size_t)(i - 1) * HD);
    int su = (i == 0) ? HD : NL * HD;
    int sm = (i == 0) ? HD : NL * HD;
    aggregate_kernel<<<(NMc * 64 + 255) / 256, 256, 0, stream>>>(offs_m, ssrc_m, xu_prev, su, agg_m, NMc);
    aggregate_kernel<<<(NUc * 64 + 255) / 256, 256, 0, stream>>>(offs_u, ssrc_u, xm_prev, sm, agg_u, NUc);
    sage_combine_kernel<<<(NMc + TILE - 1) / TILE, TILE, 0, stream>>>(
        NMc, agg_m, xm_prev, sm,
        Wl_um + (size_t)i * HD * HD, Wr_um + (size_t)i * HD * HD, b_um + (size_t)i * HD,
        outs_m + (size_t)i * HD, NL * HD);
    sage_combine_kernel<<<(NUc + TILE - 1) / TILE, TILE, 0, stream>>>(
        NUc, agg_u, xu_prev, su,
        Wl_mu + (size_t)i * HD * HD, Wr_mu + (size_t)i * HD * HD, b_mu + (size_t)i * HD,
        outs_u + (size_t)i * HD, NL * HD);
  }

  proj_kernel<<<(NUc + TILE - 1) / TILE, TILE, 0, stream>>>(NUc, outs_u, puW, pub, h_u);
  proj_kernel<<<(NMc + TILE - 1) / TILE, TILE, 0, stream>>>(NMc, outs_m, pmW, pmb, h_m);

  int lb = (ELc + TILE - 1) / TILE;
  cls1_kernel<<<lb, TILE, 0, stream>>>(h_u, h_m, lu, lm, W1, b1, y1, sum1, ssq1);
  bn_finalize_kernel<<<1, 64, 0, stream>>>(sum1, ssq1, g1, be1, 64, 1.f / ELc, scale1, shift1);
  cls2_kernel<<<lb, TILE, 0, stream>>>(y1, scale1, shift1, W2, b2, y2, sum2, ssq2);
  bn_finalize_kernel<<<1, 64, 0, stream>>>(sum2, ssq2, g2, be2, 32, 1.f / ELc, scale2, shift2);
  cls3_kernel<<<(ELc + 255) / 256, 256, 0, stream>>>(y2, scale2, shift2, W3, b3, outp);
}